// Round 1
// 125.003 us; speedup vs baseline: 1.0147x; 1.0147x over previous
//
#include <hip/hip_runtime.h>
#include <hip/hip_bf16.h>

// SnakeBrain fused kernel, round 6.
// R5 post-mortem: timed region = 2 poison fills (~86us, fixed) + kernel ~40us.
// Kernel VALU-issue floor is ~7us -> R5 was latency/serialization bound:
// 7 block barriers coupling 4 independent-snake waves, per-snake serialized
// cold x loads, edgebuf LDS round-trips for 2 boundary floats.
// R6: one wave = one snake (4 chunks of 64 nodes), ZERO __syncthreads.
// Chunk boundaries live in registers: edgeL saved from previous chunk;
// next chunk's t=0 MFMA tile computed one step ahead supplies the right
// boundary. All x loads issued upfront. Head is wave-local (LDS broadcast
// with in-wave lgkmcnt fences only). Numerics identical to R5 (bf16 3-term
// split MFMA, f32 stencils).

#define NB  4096
#define CL  256
#define HID 32
#define FIN 64
#define SPB 4     // snakes per block = waves per block; grid = NB/SPB = 1024

typedef __attribute__((ext_vector_type(8))) short    bf16x8;
typedef __attribute__((ext_vector_type(4))) float    f32x4;
typedef __attribute__((ext_vector_type(4))) unsigned u32x4;

__device__ __forceinline__ unsigned pkbf(float a, float b) {
    // packs bf16(a) in low 16, bf16(b) in high 16 (RNE, v_cvt_pk_bf16_f32)
    __hip_bfloat162 hb = __float22bfloat162_rn(make_float2(a, b));
    unsigned u; __builtin_memcpy(&u, &hb, sizeof(u));
    return u;
}
__device__ __forceinline__ float bflo(unsigned u) { return __builtin_bit_cast(float, u << 16); }
__device__ __forceinline__ float bfhi(unsigned u) { return __builtin_bit_cast(float, u & 0xffff0000u); }

// GCN chain coefficients for node n (deg incl self-loop: 3 interior, 2 ends)
__device__ __forceinline__ void gcn_coef(int n, float& nc, float& nl, float& nr) {
    const float IS3 = 0.57735026918962576f, IS2 = 0.70710678118654752f;
    const float dn = (n == 0 || n == CL - 1) ? IS2 : IS3;
    nc = dn * dn;
    nl = (n > 0)      ? dn * ((n == 1)      ? IS2 : IS3) : 0.0f;
    nr = (n < CL - 1) ? dn * ((n == CL - 2) ? IS2 : IS3) : 0.0f;
}

// in-wave LDS ordering: ds ops of one wave complete in order; fence the
// compiler and drain lgkm so cross-LANE (same wave) reads see the writes.
__device__ __forceinline__ void wave_lds_fence() {
    __builtin_amdgcn_wave_barrier();
    asm volatile("s_waitcnt lgkmcnt(0)" ::: "memory");
    __builtin_amdgcn_wave_barrier();
}

__global__ __launch_bounds__(256, 4) void snake_fused(
    const float* __restrict__ x,
    const float* __restrict__ heads,
    const float* __restrict__ body_sizes,
    const float* __restrict__ fruits,
    const float* __restrict__ W1, const float* __restrict__ b1,
    const float* __restrict__ W2, const float* __restrict__ b2,
    const float* __restrict__ Wr, const float* __restrict__ br,
    const float* __restrict__ Wa1, const float* __restrict__ ba1,
    const float* __restrict__ Wa2, const float* __restrict__ ba2,
    const float* __restrict__ Wc, const float* __restrict__ bc,
    const float* __restrict__ Wp, const float* __restrict__ bp,
    const float* __restrict__ Wv, const float* __restrict__ bv,
    float* __restrict__ out)
{
    __shared__ __align__(16) float poolLDS[SPB][HID];   // 512 B
    __shared__ __align__(16) float auxLDS[SPB][HID];    // 512 B
    __shared__ __align__(16) float catLDS[SPB][FIN];    // 1 KB

    const int blk  = blockIdx.x;
    const int w    = threadIdx.x >> 6;   // wave = snake within block
    const int lane = threadIdx.x & 63;
    const int g    = lane >> 4;          // k-group (A) / row-group (C)
    const int c    = lane & 15;          // tile col
    const int gs   = SPB * blk + w;      // global snake id

    // ---- B fragments for W2 (split bf16), built once per wave ----
    // B layout: B[k=8g+j][n=c+16nt]
    bf16x8 Bh[2], Bl[2];
    #pragma unroll
    for (int nt = 0; nt < 2; ++nt) {
        unsigned hh[4], ll[4];
        #pragma unroll
        for (int p = 0; p < 4; ++p) {
            const float wa = W2[(8 * g + 2 * p)     * HID + c + 16 * nt];
            const float wb = W2[(8 * g + 2 * p + 1) * HID + c + 16 * nt];
            const unsigned hu = pkbf(wa, wb);
            hh[p] = hu;
            ll[p] = pkbf(wa - bflo(hu), wb - bfhi(hu));
        }
        u32x4 H = {hh[0], hh[1], hh[2], hh[3]};
        u32x4 L = {ll[0], ll[1], ll[2], ll[3]};
        Bh[nt] = __builtin_bit_cast(bf16x8, H);
        Bl[nt] = __builtin_bit_cast(bf16x8, L);
    }
    const float b2v0 = b2[c], b2v1 = b2[c + 16];

    // W1/b1 slices for this lane's A-channels 8g..8g+7
    const float4 W1a0 = *reinterpret_cast<const float4*>(W1 + 8 * g);
    const float4 W1a1 = *reinterpret_cast<const float4*>(W1 + 8 * g + 4);
    const float4 W1b0 = *reinterpret_cast<const float4*>(W1 + HID + 8 * g);
    const float4 W1b1 = *reinterpret_cast<const float4*>(W1 + HID + 8 * g + 4);
    const float4 b1v0 = *reinterpret_cast<const float4*>(b1 + 8 * g);
    const float4 b1v1 = *reinterpret_cast<const float4*>(b1 + 8 * g + 4);

    const float2* xs = reinterpret_cast<const float2*>(x) + gs * CL;

    // ---- stencil1 (S and W1 commute) for all 4 chunks; loads upfront ----
    float sxx[4], sxy[4];
    {
        float2 xc4[4], xl4[4], xr4[4];
        #pragma unroll
        for (int k = 0; k < 4; ++k) {
            const int n = 64 * k + lane;
            xc4[k] = xs[n];
            xl4[k] = xs[n - (n > 0)];
            xr4[k] = xs[n + (n < CL - 1)];
        }
        #pragma unroll
        for (int k = 0; k < 4; ++k) {
            const int n = 64 * k + lane;
            float ncd, nld, nrd;
            gcn_coef(n, ncd, nld, nrd);
            sxx[k] = ncd * xc4[k].x + nld * xl4[k].x + nrd * xr4[k].x;
            sxy[k] = ncd * xc4[k].y + nld * xl4[k].y + nrd * xr4[k].y;
        }
    }

    // one 16-node MFMA tile: r1 channels 8g..8g+7 of node 64k+16t+c,
    // bf16 3-term split into 2x3 MFMAs (nt=0/1). d0/d1 fully overwritten.
    auto mfma_tile = [&](float sxk, float syk, int t, f32x4& d0, f32x4& d1) {
        const float sa = __shfl(sxk, 16 * t + c, 64);
        const float sb = __shfl(syk, 16 * t + c, 64);
        const float r0 = fmaxf(fmaf(sa, W1a0.x, fmaf(sb, W1b0.x, b1v0.x)), 0.f);
        const float r1 = fmaxf(fmaf(sa, W1a0.y, fmaf(sb, W1b0.y, b1v0.y)), 0.f);
        const float r2 = fmaxf(fmaf(sa, W1a0.z, fmaf(sb, W1b0.z, b1v0.z)), 0.f);
        const float r3 = fmaxf(fmaf(sa, W1a0.w, fmaf(sb, W1b0.w, b1v0.w)), 0.f);
        const float r4 = fmaxf(fmaf(sa, W1a1.x, fmaf(sb, W1b1.x, b1v1.x)), 0.f);
        const float r5 = fmaxf(fmaf(sa, W1a1.y, fmaf(sb, W1b1.y, b1v1.y)), 0.f);
        const float r6 = fmaxf(fmaf(sa, W1a1.z, fmaf(sb, W1b1.z, b1v1.z)), 0.f);
        const float r7 = fmaxf(fmaf(sa, W1a1.w, fmaf(sb, W1b1.w, b1v1.w)), 0.f);
        const unsigned h0 = pkbf(r0, r1), h1 = pkbf(r2, r3);
        const unsigned h2 = pkbf(r4, r5), h3 = pkbf(r6, r7);
        const unsigned q0 = pkbf(r0 - bflo(h0), r1 - bfhi(h0));
        const unsigned q1 = pkbf(r2 - bflo(h1), r3 - bfhi(h1));
        const unsigned q2 = pkbf(r4 - bflo(h2), r5 - bfhi(h2));
        const unsigned q3 = pkbf(r6 - bflo(h3), r7 - bfhi(h3));
        u32x4 HU = {h0, h1, h2, h3};
        u32x4 LU = {q0, q1, q2, q3};
        const bf16x8 ah = __builtin_bit_cast(bf16x8, HU);
        const bf16x8 al = __builtin_bit_cast(bf16x8, LU);
        const f32x4 z = {0.f, 0.f, 0.f, 0.f};
        d0 = __builtin_amdgcn_mfma_f32_16x16x32_bf16(ah, Bh[0], z,  0, 0, 0);
        d0 = __builtin_amdgcn_mfma_f32_16x16x32_bf16(al, Bh[0], d0, 0, 0, 0);
        d0 = __builtin_amdgcn_mfma_f32_16x16x32_bf16(ah, Bl[0], d0, 0, 0, 0);
        d1 = __builtin_amdgcn_mfma_f32_16x16x32_bf16(ah, Bh[1], z,  0, 0, 0);
        d1 = __builtin_amdgcn_mfma_f32_16x16x32_bf16(al, Bh[1], d1, 0, 0, 0);
        d1 = __builtin_amdgcn_mfma_f32_16x16x32_bf16(ah, Bl[1], d1, 0, 0, 0);
    };

    // C/D layout: lane (g,c) reg r of tile t = node 64k+16t+4g+r, ch c+16nt
    f32x4 accCur[4][2];   // current chunk, all 4 t-tiles
    f32x4 accN0[2];       // next chunk's t=0 tile (right boundary supplier)

    #pragma unroll
    for (int t = 0; t < 4; ++t)
        mfma_tile(sxx[0], sxy[0], t, accCur[t][0], accCur[t][1]);

    float edgeL0 = 0.f, edgeL1 = 0.f;   // prev chunk node 64k-1 h2pre (lanes 48..63)
    float sum0 = 0.f, sum1 = 0.f;       // pool partials, ch c / c+16

    const float THIRD = 0.33333333333333333f;
    const float I23   = 0.40824829046386302f;   // 1/sqrt(6)

    #pragma unroll
    for (int k = 0; k < 4; ++k) {
        if (k < 3) mfma_tile(sxx[k + 1], sxy[k + 1], 0, accN0[0], accN0[1]);

        const bool fixL = (k == 0) && (g == 0);   // nodes 0/1 end coefficients
        const bool fixR = (k == 3) && (g == 3);   // nodes 254/255

        #pragma unroll
        for (int t = 0; t < 4; ++t) {
            float c0 = THIRD, r0c = THIRD, l1c = THIRD;
            float c3 = THIRD, l3c = THIRD, r2c = THIRD;
            if (t == 0) { c0 = fixL ? 0.5f : THIRD; r0c = fixL ? I23 : THIRD; l1c = fixL ? I23 : THIRD; }
            if (t == 3) { c3 = fixR ? 0.5f : THIRD; l3c = fixR ? I23 : THIRD; r2c = fixR ? I23 : THIRD; }
            #pragma unroll
            for (int nt = 0; nt < 2; ++nt) {
                const f32x4 v = accCur[t][nt];
                // left neighbor of reg0: sender role g==3 provides acc[t-1][3]
                const float Lsend = (g == 3) ? accCur[(t > 0) ? t - 1 : 0][nt][3] : accCur[t][nt][3];
                const int   Lsrc  = (g == 0) ? (c + 48) : (lane - 16);
                float L = __shfl(Lsend, Lsrc, 64);
                if (t == 0) {
                    float eL = __shfl((nt == 0) ? edgeL0 : edgeL1, 48 + c, 64);
                    eL = (k > 0) ? eL : 0.f;
                    L = (g == 0) ? eL : L;
                }
                // right neighbor of reg3: sender role g==0 provides acc[t+1][0]
                const float Rsend = (g == 0) ? accCur[(t < 3) ? t + 1 : 3][nt][0] : accCur[t][nt][0];
                const int   Rsrc  = (g == 3) ? c : (lane + 16);
                float R = __shfl(Rsend, Rsrc, 64);
                if (t == 3) {
                    float eR = __shfl(accN0[nt][0], c, 64);
                    eR = (k < 3) ? eR : 0.f;
                    R = (g == 3) ? eR : R;
                }
                const float bb = (nt == 0) ? b2v0 : b2v1;
                const float h0 = fmaxf(fmaf(c0,    v[0], fmaf(THIRD, L,    fmaf(r0c,   v[1], bb))), 0.f);
                const float h1 = fmaxf(fmaf(THIRD, v[1], fmaf(l1c,   v[0], fmaf(THIRD, v[2], bb))), 0.f);
                const float h2 = fmaxf(fmaf(THIRD, v[2], fmaf(THIRD, v[1], fmaf(r2c,   v[3], bb))), 0.f);
                const float h3 = fmaxf(fmaf(c3,    v[3], fmaf(l3c,   v[2], fmaf(THIRD, R,    bb))), 0.f);
                const float hs = (h0 + h1) + (h2 + h3);
                if (nt == 0) sum0 += hs; else sum1 += hs;
            }
        }

        // save this chunk's right boundary (meaningful in lanes 48..63),
        // then rotate: next chunk's t0 was already computed into accN0.
        edgeL0 = accCur[3][0][3];
        edgeL1 = accCur[3][1][3];
        if (k < 3) {
            accCur[0][0] = accN0[0];
            accCur[0][1] = accN0[1];
            #pragma unroll
            for (int t = 1; t < 4; ++t)
                mfma_tile(sxx[k + 1], sxy[k + 1], t, accCur[t][0], accCur[t][1]);
        }
    }

    // pool reduce over the 4 g-groups -> every lane holds pooled[c], pooled[c+16]
    sum0 += __shfl_xor(sum0, 16, 64); sum0 += __shfl_xor(sum0, 32, 64);
    sum1 += __shfl_xor(sum1, 16, 64); sum1 += __shfl_xor(sum1, 32, 64);

    // ================= head: fully wave-local, no block barriers =================
    if (lane < 16) {
        poolLDS[w][lane]      = sum0 * (1.0f / CL);
        poolLDS[w][lane + 16] = sum1 * (1.0f / CL);
    } else if (lane >= HID) {
        const int cc = lane - HID;
        float a = ba1[cc];
        a = fmaf(heads[2 * gs],      Wa1[0 * HID + cc], a);
        a = fmaf(heads[2 * gs + 1],  Wa1[1 * HID + cc], a);
        a = fmaf(body_sizes[gs],     Wa1[2 * HID + cc], a);
        a = fmaf(fruits[2 * gs],     Wa1[3 * HID + cc], a);
        a = fmaf(fruits[2 * gs + 1], Wa1[4 * HID + cc], a);
        auxLDS[w][cc] = fmaxf(a, 0.f);
    }
    wave_lds_fence();

    if (lane < HID) {     // body_emb = pooled @ Wr + br (no relu)
        float be0 = br[lane], be1 = 0.f;
        const float4* p4 = reinterpret_cast<const float4*>(poolLDS[w]);
        #pragma unroll
        for (int k4 = 0; k4 < 8; ++k4) {
            const float4 p = p4[k4];
            be0 = fmaf(p.x, Wr[(4 * k4 + 0) * HID + lane], be0);
            be1 = fmaf(p.y, Wr[(4 * k4 + 1) * HID + lane], be1);
            be0 = fmaf(p.z, Wr[(4 * k4 + 2) * HID + lane], be0);
            be1 = fmaf(p.w, Wr[(4 * k4 + 3) * HID + lane], be1);
        }
        catLDS[w][lane] = be0 + be1;
    } else {              // aux2 = relu(aux1 @ Wa2 + ba2)
        const int cc = lane - HID;
        float a0 = ba2[cc], a1 = 0.f;
        const float4* p4 = reinterpret_cast<const float4*>(auxLDS[w]);
        #pragma unroll
        for (int k4 = 0; k4 < 8; ++k4) {
            const float4 p = p4[k4];
            a0 = fmaf(p.x, Wa2[(4 * k4 + 0) * HID + cc], a0);
            a1 = fmaf(p.y, Wa2[(4 * k4 + 1) * HID + cc], a1);
            a0 = fmaf(p.z, Wa2[(4 * k4 + 2) * HID + cc], a0);
            a1 = fmaf(p.w, Wa2[(4 * k4 + 3) * HID + cc], a1);
        }
        catLDS[w][lane] = fmaxf(a0 + a1, 0.f);
    }
    wave_lds_fence();

    // combined = relu(cat @ Wc + bc); then logits/value via butterfly
    {
        float cb0 = bc[lane], cb1 = 0.f;
        const float4* c4p = reinterpret_cast<const float4*>(catLDS[w]);
        #pragma unroll
        for (int k4 = 0; k4 < 16; ++k4) {
            const float4 p = c4p[k4];
            cb0 = fmaf(p.x, Wc[(4 * k4 + 0) * FIN + lane], cb0);
            cb1 = fmaf(p.y, Wc[(4 * k4 + 1) * FIN + lane], cb1);
            cb0 = fmaf(p.z, Wc[(4 * k4 + 2) * FIN + lane], cb0);
            cb1 = fmaf(p.w, Wc[(4 * k4 + 3) * FIN + lane], cb1);
        }
        const float cb = fmaxf(cb0 + cb1, 0.f);
        float s0 = cb * Wp[lane * 5 + 0];
        float s1 = cb * Wp[lane * 5 + 1];
        float s2 = cb * Wp[lane * 5 + 2];
        float s3 = cb * Wp[lane * 5 + 3];
        float s4 = cb * Wp[lane * 5 + 4];
        float s5 = cb * Wv[lane];
        #pragma unroll
        for (int m = 1; m <= 32; m <<= 1) {
            s0 += __shfl_xor(s0, m, 64);
            s1 += __shfl_xor(s1, m, 64);
            s2 += __shfl_xor(s2, m, 64);
            s3 += __shfl_xor(s3, m, 64);
            s4 += __shfl_xor(s4, m, 64);
            s5 += __shfl_xor(s5, m, 64);
        }
        if (lane == 0) {
            out[gs * 5 + 0] = s0 + bp[0];
            out[gs * 5 + 1] = s1 + bp[1];
            out[gs * 5 + 2] = s2 + bp[2];
            out[gs * 5 + 3] = s3 + bp[3];
            out[gs * 5 + 4] = s4 + bp[4];
            out[NB * 5 + gs] = s5 + bv[0];
        }
    }
}

extern "C" void kernel_launch(void* const* d_in, const int* in_sizes, int n_in,
                              void* d_out, int out_size, void* d_ws, size_t ws_size,
                              hipStream_t stream) {
    const float* x          = (const float*)d_in[0];
    const float* heads      = (const float*)d_in[1];
    const float* body_sizes = (const float*)d_in[2];
    const float* fruits     = (const float*)d_in[3];
    const float* W1 = (const float*)d_in[4];
    const float* b1 = (const float*)d_in[5];
    const float* W2 = (const float*)d_in[6];
    const float* b2 = (const float*)d_in[7];
    const float* Wr = (const float*)d_in[8];
    const float* br = (const float*)d_in[9];
    const float* Wa1 = (const float*)d_in[10];
    const float* ba1 = (const float*)d_in[11];
    const float* Wa2 = (const float*)d_in[12];
    const float* ba2 = (const float*)d_in[13];
    const float* Wc = (const float*)d_in[14];
    const float* bc = (const float*)d_in[15];
    const float* Wp = (const float*)d_in[16];
    const float* bp = (const float*)d_in[17];
    const float* Wv = (const float*)d_in[18];
    const float* bv = (const float*)d_in[19];

    float* out = (float*)d_out;
    snake_fused<<<NB / SPB, CL, 0, stream>>>(
        x, heads, body_sizes, fruits,
        W1, b1, W2, b2, Wr, br, Wa1, ba1, Wa2, ba2,
        Wc, bc, Wp, bp, Wv, bv, out);
}